// Round 10
// baseline (570.810 us; speedup 1.0000x reference)
//
#include <hip/hip_runtime.h>

// Res_MCNN_branch2 on gfx950 — all convs f16 MFMA implicit-GEMM (16x16x32).
// R19 = R18 with (1) conv1 staging reverted to R17 float4 form (R18's
// float2 "conflict fix" regressed 96->102: conflicts are from frag b64
// reads (inherent odd-8B offsets), not staging writes; float2 doubled
// load-instruction count for nothing), and (2) __launch_bounds__(256,3)
// on conv2/3/4: the K-fold deleted the frag window, so per-wave liveness
// is now acc-dominated (conv2 ~160, conv3/4 ~95 regs) and 3 waves/SIMD
// fits without spill — occupancy finally addressable without adding state.
// Failure ledger (conv2, all reverted): R11 gload_lds DMA (22x FETCH),
// R12 multi-tile (L2 thrash), R14 g-split forced-3 on OLD fat structure
// (spill), R15 2-row waves (2x overhead), R16 direct-global (spill),
// R18 conv1 float2 staging (instr count up, conflicts unchanged).
// Layouts: P1 NHWC24, P2 NHWC48, X3 NHWC24. conv4+conv5 fused (R13).

typedef _Float16 half_t;
typedef _Float16 half8 __attribute__((ext_vector_type(8)));
typedef float floatx4 __attribute__((ext_vector_type(4)));

#define IN_H 768
#define IN_W 1024
#define P1H 384
#define P1W 512
#define P2H 192
#define P2W 256

// workspace offsets (bytes)
#define OFF_P2 0ULL                 // f16 [8][192][256][48] = 37,748,736
#define OFF_P1 44040192ULL          // f16 [8][384][512][24] = 75,497,472
#define OFF_X3 44040192ULL          // reuse P1 region after conv2
#define OFF_W2 119537664ULL         // f16 [5][4][48][32] = 30,720 el (K-folded)
#define OFF_W3 119599104ULL         // f16 [5][8][32][32] = 40,960 el (K-folded)
#define OFF_W4 119681024ULL         // f16 [5][4][16][32] = 10,240 el (K-folded)
#define OFF_W1 119701504ULL         // f16 [7][32][32]    = 7,168 el

union PK4 { half_t h[4]; uint2 u; };
union U8 { half8 v; uint2 u[2]; };

// ---------------- weight pre-pack (fp32 OIHW -> f16 packed, linear) ----------------
__global__ __launch_bounds__(256) void pack_weights(
    const float* __restrict__ w2, const float* __restrict__ w3,
    const float* __restrict__ w4, const float* __restrict__ w1,
    half_t* __restrict__ wp2, half_t* __restrict__ wp3, half_t* __restrict__ wp4,
    half_t* __restrict__ wp1)
{
  int t = blockIdx.x * 256 + threadIdx.x;
  if (t < 30720) {                       // conv2 K-folded: [5 ky][4 kk][48 oc][32 k]
    int ky = t / 6144, r = t % 6144;
    int kk = r / 1536, r2 = r % 1536, oc = r2 >> 5, k = r2 & 31;
    int o = kk * 32 + k, p = o / 24, c = o % 24;   // pixel offset p (=kx), channel c
    float v = (oc < 40 && c < 20 && p < 5) ? w2[(oc * 20 + c) * 25 + ky * 5 + p] : 0.f;
    wp2[t] = (half_t)v;
  } else if (t < 71680) {                // conv3 K-folded: [5 ky][8 kk][32 oc][32 k]
    int u = t - 30720;
    int ky = u / 8192, r = u % 8192;
    int kk = r / 1024, r2 = r % 1024, oc = r2 >> 5, k = r2 & 31;
    int o = kk * 32 + k, p = o / 48, c = o % 48;   // pixel p, channel c in NHWC48
    float v = (oc < 20 && c < 40 && p < 5) ? w3[(oc * 40 + c) * 25 + ky * 5 + p] : 0.f;
    wp3[u] = (half_t)v;
  } else if (t < 81920) {                // conv4 K-folded: [5 ky][4 kk][16 oc][32 k]
    int u = t - 71680;
    int ky = u / 2048, r = u % 2048;
    int kk = r / 512, r2 = r % 512, oc = r2 >> 5, k = r2 & 31;
    int o = kk * 32 + k, p = o / 24, c = o % 24;
    float v = (oc < 10 && c < 20 && p < 5) ? w4[(oc * 20 + c) * 25 + ky * 5 + p] : 0.f;
    wp4[u] = (half_t)v;
  } else if (t < 89088) {                // conv1: [7][32][32], k = kx*4+c (unchanged)
    int u = t - 81920;
    int ky = u / 1024, r = u % 1024, oc = r >> 5, k = r & 31;
    int kx = k >> 2, c = k & 3;
    float v = (oc < 20 && c < 3 && kx < 7) ? w1[((oc * 3 + c) * 7 + ky) * 7 + kx] : 0.f;
    wp1[u] = (half_t)v;
  }
}

// ---------------- conv1 (3->20, 7x7, pad 3) MFMA + relu + pool -> P1 f16 NHWC24 ----------------
// 32-row tile, stage once (38x40 region, origin tx0-4 for float4 alignment),
// two K-loop passes p=0,1. Interior blocks: unguarded float4 staging (R17).
__global__ __launch_bounds__(256) void conv1_mfma(
    const float* __restrict__ in, const half_t* __restrict__ wp,
    const float* __restrict__ bias, half_t* __restrict__ P1)
{
  __shared__ __align__(16) half_t ltile[38 * 40 * 4];   // 12160 B, row stride 40 px
  const int b = blockIdx.z, ty0 = blockIdx.y * 32, tx0 = blockIdx.x * 32;
  const int tid = threadIdx.x;
  const int HW1 = IN_H * IN_W;

  const float* p0 = in + (size_t)b * 3 * HW1;
  const bool interior = (blockIdx.x >= 1) && (blockIdx.x <= 30) &&
                        (blockIdx.y >= 1) && (blockIdx.y <= 22);
  if (interior) {
    for (int i = tid; i < 380; i += 256) {              // 38 rows x 10 float4
      int r = i / 10, c4 = i - r * 10;
      const float* pr = p0 + (size_t)(ty0 - 3 + r) * IN_W + (tx0 - 4 + 4 * c4);
      float4 v0 = *(const float4*)(pr);
      float4 v1 = *(const float4*)(pr + HW1);
      float4 v2 = *(const float4*)(pr + 2 * HW1);
      PK4 a0, a1, a2, a3;
      a0.h[0] = (half_t)v0.x; a0.h[1] = (half_t)v1.x; a0.h[2] = (half_t)v2.x; a0.h[3] = (half_t)0.f;
      a1.h[0] = (half_t)v0.y; a1.h[1] = (half_t)v1.y; a1.h[2] = (half_t)v2.y; a1.h[3] = (half_t)0.f;
      a2.h[0] = (half_t)v0.z; a2.h[1] = (half_t)v1.z; a2.h[2] = (half_t)v2.z; a2.h[3] = (half_t)0.f;
      a3.h[0] = (half_t)v0.w; a3.h[1] = (half_t)v1.w; a3.h[2] = (half_t)v2.w; a3.h[3] = (half_t)0.f;
      uint4* dst = (uint4*)(ltile + (r * 40 + 4 * c4) * 4);
      dst[0] = make_uint4(a0.u.x, a0.u.y, a1.u.x, a1.u.y);
      dst[1] = make_uint4(a2.u.x, a2.u.y, a3.u.x, a3.u.y);
    }
  } else {
    for (int i = tid; i < 1520; i += 256) {             // 38 rows x 40 cols, guarded
      int r = i / 40, c = i - r * 40;
      int gy = ty0 - 3 + r, gx = tx0 - 4 + c;
      float v0 = 0.f, v1 = 0.f, v2 = 0.f;
      if (gy >= 0 && gy < IN_H && (unsigned)gx < (unsigned)IN_W) {
        size_t o = (size_t)gy * IN_W + gx;
        v0 = p0[o];
        v1 = p0[o + HW1];
        v2 = p0[o + 2 * HW1];
      }
      PK4 pk;
      pk.h[0] = (half_t)v0; pk.h[1] = (half_t)v1;
      pk.h[2] = (half_t)v2; pk.h[3] = (half_t)0.f;
      *(uint2*)(ltile + (r * 40 + c) * 4) = pk.u;
    }
  }
  __syncthreads();

  const int wv = tid >> 6, ln = tid & 63, q = ln >> 4, nl = ln & 15;
  const int cbase = (2 * nl + 2 * q + 1) * 4;           // +1: tile origin tx0-4
  const half_t* wA = wp + nl * 32 + q * 8;

  floatx4 bv[2];
  #pragma unroll
  for (int mt = 0; mt < 2; ++mt)
    #pragma unroll
    for (int r = 0; r < 4; ++r) {
      int oc = mt * 16 + q * 4 + r;
      bv[mt][r] = (oc < 20) ? bias[oc] : 0.f;
    }
  const int pc = (tx0 >> 1) + nl;

  #pragma unroll
  for (int p = 0; p < 2; ++p) {
    const int rbase = p * 16 + 4 * wv;            // ltile row of this pass/wave
    U8 frag[4][2];
    #pragma unroll
    for (int d = 0; d < 4; ++d) {
      const half_t* rp = ltile + (rbase + d) * 160 + cbase;
      #pragma unroll
      for (int phx = 0; phx < 2; ++phx) {
        frag[d][phx].u[0] = *(const uint2*)(rp + phx * 4);
        frag[d][phx].u[1] = *(const uint2*)(rp + phx * 4 + 4);
      }
    }
    half8 Abuf[2][2];
    Abuf[0][0] = *(const half8*)(wA);
    Abuf[0][1] = *(const half8*)(wA + 512);
    floatx4 acc[2][8];
    #pragma unroll
    for (int mt = 0; mt < 2; ++mt)
      #pragma unroll
      for (int j = 0; j < 8; ++j) acc[mt][j] = (floatx4){0.f, 0.f, 0.f, 0.f};

    #pragma unroll
    for (int ky = 0; ky < 7; ++ky) {
      if (ky < 6) {
        Abuf[(ky + 1) & 1][0] = *(const half8*)(wA + (ky + 1) * 1024);
        Abuf[(ky + 1) & 1][1] = *(const half8*)(wA + (ky + 1) * 1024 + 512);
      }
      #pragma unroll
      for (int j = 0; j < 8; ++j) {
        const int g = j >> 2, ph = j & 3, phy = ph >> 1, phx = ph & 1;
        half8 B = frag[(2 * g + phy + ky) & 3][phx].v;
        acc[0][j] = __builtin_amdgcn_mfma_f32_16x16x32_f16(Abuf[ky & 1][0], B, acc[0][j], 0, 0, 0);
        acc[1][j] = __builtin_amdgcn_mfma_f32_16x16x32_f16(Abuf[ky & 1][1], B, acc[1][j], 0, 0, 0);
      }
      if (ky < 6) {                               // slide: ltile row rbase+ky+4 -> slot ky&3
        const half_t* rp = ltile + (rbase + ky + 4) * 160 + cbase;
        #pragma unroll
        for (int phx = 0; phx < 2; ++phx) {
          frag[ky & 3][phx].u[0] = *(const uint2*)(rp + phx * 4);
          frag[ky & 3][phx].u[1] = *(const uint2*)(rp + phx * 4 + 4);
        }
      }
    }

    const int pr0 = (ty0 >> 1) + 8 * p + 2 * wv;
    #pragma unroll
    for (int g = 0; g < 2; ++g) {
      size_t pxbase = (((size_t)b * P1H + pr0 + g) * P1W + pc) * 24;
      PK4 pk0;
      #pragma unroll
      for (int r = 0; r < 4; ++r) {
        float x = fmaxf(fmaxf(acc[0][g * 4 + 0][r], acc[0][g * 4 + 1][r]),
                        fmaxf(acc[0][g * 4 + 2][r], acc[0][g * 4 + 3][r]));
        pk0.h[r] = (half_t)fmaxf(x + bv[0][r], 0.f);
      }
      *(uint2*)(P1 + pxbase + q * 4) = pk0.u;           // oc 0..15
      if (q < 2) {                                      // oc 16..19 real, 20..23 = 0
        PK4 pk1;
        #pragma unroll
        for (int r = 0; r < 4; ++r) {
          float x = fmaxf(fmaxf(acc[1][g * 4 + 0][r], acc[1][g * 4 + 1][r]),
                          fmaxf(acc[1][g * 4 + 2][r], acc[1][g * 4 + 3][r]));
          pk1.h[r] = (half_t)fmaxf(x + bv[1][r], 0.f);
        }
        *(uint2*)(P1 + pxbase + 16 + q * 4) = pk1.u;
      }
    }
  }
}

// ---------------- conv2 (20->40, 5x5) MFMA + relu + pool -> P2 f16 NHWC48 ----------------
// K-folded (R17): 4 K=32 steps per ky over the contiguous 120-half span.
// Output NHWC48: mt=0..2 covers exactly 48 oc (40 real + 8 zero-weight pad).
// (256,3): K-folded liveness (~96 AGPR + ~65 VGPR) fits 170-reg cap.
__global__ __launch_bounds__(256, 3) void conv2_mfma(
    const half_t* __restrict__ P1, const half_t* __restrict__ wp,
    const float* __restrict__ bias, half_t* __restrict__ P2)
{
  __shared__ __align__(16) half_t lin[20 * 36 * 24 + 16];   // 34592 B
  const int b = blockIdx.z, ty0 = blockIdx.y * 16, tx0 = blockIdx.x * 32;
  const int tid = threadIdx.x;
  if (tid < 16) lin[20 * 36 * 24 + tid] = (half_t)0.f;
  for (int i = tid; i < 2160; i += 256) {              // 720 px x 3 uint4
    int px = i / 3, part = i - px * 3;
    int row = px / 36, col = px - row * 36;
    int gy = ty0 - 2 + row, gx = tx0 - 2 + col;
    uint4 v = make_uint4(0, 0, 0, 0);
    if (gy >= 0 && gy < P1H && (unsigned)gx < (unsigned)P1W)
      v = *(const uint4*)(P1 + (((size_t)b * P1H + gy) * P1W + gx) * 24 + part * 8);
    *(uint4*)(lin + px * 24 + part * 8) = v;
  }
  __syncthreads();

  const int wv = tid >> 6, ln = tid & 63, q = ln >> 4, nl = ln & 15;
  const half_t* cb0 = lin + 2 * nl * 24 + q * 8;       // span base, phx=0
  const half_t* wA = wp + nl * 32 + q * 8;

  floatx4 acc[3][8];
  #pragma unroll
  for (int mt = 0; mt < 3; ++mt)
    #pragma unroll
    for (int j = 0; j < 8; ++j) acc[mt][j] = (floatx4){0.f, 0.f, 0.f, 0.f};

  #pragma unroll
  for (int ky = 0; ky < 5; ++ky) {
    #pragma unroll
    for (int kk = 0; kk < 4; ++kk) {
      const half_t* wt = wA + (ky * 4 + kk) * 1536;
      half8 A0 = *(const half8*)(wt);
      half8 A1 = *(const half8*)(wt + 512);
      half8 A2 = *(const half8*)(wt + 1024);
      #pragma unroll
      for (int j = 0; j < 8; ++j) {
        const int g = j >> 2, phy = (j >> 1) & 1, phx = j & 1;
        half8 B = *(const half8*)(cb0 + (4 * wv + 2 * g + phy + ky) * 864 + phx * 24 + kk * 32);
        acc[0][j] = __builtin_amdgcn_mfma_f32_16x16x32_f16(A0, B, acc[0][j], 0, 0, 0);
        acc[1][j] = __builtin_amdgcn_mfma_f32_16x16x32_f16(A1, B, acc[1][j], 0, 0, 0);
        acc[2][j] = __builtin_amdgcn_mfma_f32_16x16x32_f16(A2, B, acc[2][j], 0, 0, 0);
      }
    }
  }

  floatx4 bv[3];
  #pragma unroll
  for (int mt = 0; mt < 3; ++mt)
    #pragma unroll
    for (int r = 0; r < 4; ++r) {
      int oc = mt * 16 + q * 4 + r;
      bv[mt][r] = (oc < 40) ? bias[oc] : 0.f;
    }
  const int pr0 = (ty0 >> 1) + 2 * wv;
  const int pc = (tx0 >> 1) + nl;
  #pragma unroll
  for (int g = 0; g < 2; ++g) {
    size_t pxbase = (((size_t)b * P2H + pr0 + g) * P2W + pc) * 48;
    #pragma unroll
    for (int mt = 0; mt < 3; ++mt) {
      PK4 pk;
      #pragma unroll
      for (int r = 0; r < 4; ++r) {
        float x = fmaxf(fmaxf(acc[mt][g * 4 + 0][r], acc[mt][g * 4 + 1][r]),
                        fmaxf(acc[mt][g * 4 + 2][r], acc[mt][g * 4 + 3][r]));
        pk.h[r] = (half_t)fmaxf(x + bv[mt][r], 0.f);   // oc 40..47: 0+0 -> 0 pad
      }
      *(uint2*)(P2 + pxbase + mt * 16 + q * 4) = pk.u;
    }
  }
}

// ---------------- conv3 (40->20, 5x5) MFMA + relu -> X3 f16 NHWC24 ----------------
// K-folded: per ky the 5 taps are one contiguous 240-half NHWC48 span ->
// 8 K=32 steps (was 10). Weights [5][8][32][32], slot o -> (px o/48, ch o%48),
// zero where ch>=40 or px>=5. Worst read = half 20751 < 20752 (zero tail).
__global__ __launch_bounds__(256, 3) void conv3_mfma(
    const half_t* __restrict__ P2, const half_t* __restrict__ wp,
    const float* __restrict__ bias, half_t* __restrict__ X3)
{
  __shared__ __align__(16) half_t lin[12 * 36 * 48 + 16];   // 41504 B
  const int b = blockIdx.z, ty0 = blockIdx.y * 8, tx0 = blockIdx.x * 32;
  const int tid = threadIdx.x;
  if (tid < 16) lin[12 * 36 * 48 + tid] = (half_t)0.f;
  for (int i = tid; i < 2592; i += 256) {              // 432 px x 6 uint4
    int px = i / 6, part = i - px * 6;
    int row = px / 36, col = px - row * 36;
    int gy = ty0 - 2 + row, gx = tx0 - 2 + col;
    uint4 v = make_uint4(0, 0, 0, 0);
    if (gy >= 0 && gy < P2H && (unsigned)gx < (unsigned)P2W)
      v = *(const uint4*)(P2 + (((size_t)b * P2H + gy) * P2W + gx) * 48 + part * 8);
    *(uint4*)(lin + px * 48 + part * 8) = v;
  }
  __syncthreads();

  const int wv = tid >> 6, ln = tid & 63, q = ln >> 4, nl = ln & 15;
  const half_t* cb0 = lin + 2 * nl * 48 + q * 8;       // span base, phx=0
  const half_t* wA = wp + nl * 32 + q * 8;

  floatx4 acc[2][4];
  #pragma unroll
  for (int mt = 0; mt < 2; ++mt)
    #pragma unroll
    for (int j = 0; j < 4; ++j) acc[mt][j] = (floatx4){0.f, 0.f, 0.f, 0.f};

  #pragma unroll
  for (int ky = 0; ky < 5; ++ky) {
    #pragma unroll
    for (int kk = 0; kk < 8; ++kk) {
      const half_t* wt = wA + (ky * 8 + kk) * 1024;
      half8 A0 = *(const half8*)(wt);
      half8 A1 = *(const half8*)(wt + 512);
      #pragma unroll
      for (int j = 0; j < 4; ++j) {
        const int phy = j >> 1, phx = j & 1;
        half8 B = *(const half8*)(cb0 + (2 * wv + phy + ky) * 1728 + phx * 48 + kk * 32);
        acc[0][j] = __builtin_amdgcn_mfma_f32_16x16x32_f16(A0, B, acc[0][j], 0, 0, 0);
        acc[1][j] = __builtin_amdgcn_mfma_f32_16x16x32_f16(A1, B, acc[1][j], 0, 0, 0);
      }
    }
  }

  floatx4 bv[2];
  #pragma unroll
  for (int mt = 0; mt < 2; ++mt)
    #pragma unroll
    for (int r = 0; r < 4; ++r) {
      int oc = mt * 16 + q * 4 + r;
      bv[mt][r] = (oc < 20) ? bias[oc] : 0.f;
    }
  #pragma unroll
  for (int j = 0; j < 4; ++j) {
    const int phy = j >> 1, phx = j & 1;
    int y = ty0 + 2 * wv + phy, x = tx0 + 2 * nl + phx;
    size_t pxbase = (((size_t)b * P2H + y) * P2W + x) * 24;
    #pragma unroll
    for (int mt = 0; mt < 2; ++mt) {
      if (mt == 1 && q >= 2) continue;                 // record is 24 halves
      floatx4 v = acc[mt][j];
      PK4 pk;
      #pragma unroll
      for (int r = 0; r < 4; ++r) pk.h[r] = (half_t)fmaxf(v[r] + bv[mt][r], 0.f);
      *(uint2*)(X3 + pxbase + mt * 16 + q * 4) = pk.u; // oc 20..23 auto-zero
    }
  }
}

// ---------------- conv4 (20->10, 5x5) + conv5 (10->1, 1x1) + gray residual + relu ----------------
// K-folded (R17, mt=1): 160 MFMA/wave. X3 records 24 halves.
// Fused epilogue: q-lanes hold the same pixel (different oc) -> per-lane w5
// partial, shfl_xor(16)+shfl_xor(32) reduce, q==0 adds gray + writes out.
__global__ __launch_bounds__(256, 3) void conv4_mfma(
    const half_t* __restrict__ X3, const half_t* __restrict__ wp,
    const float* __restrict__ bias, const float* __restrict__ w5,
    const float* __restrict__ b5, const float* __restrict__ in,
    float* __restrict__ out)
{
  __shared__ __align__(16) half_t lin[20 * 36 * 24 + 16];   // 34592 B
  const int b = blockIdx.z, ty0 = blockIdx.y * 16, tx0 = blockIdx.x * 32;
  const int tid = threadIdx.x;
  if (tid < 16) lin[20 * 36 * 24 + tid] = (half_t)0.f;
  for (int i = tid; i < 2160; i += 256) {
    int px = i / 3, part = i - px * 3;
    int row = px / 36, col = px - row * 36;
    int gy = ty0 - 2 + row, gx = tx0 - 2 + col;
    uint4 v = make_uint4(0, 0, 0, 0);
    if (gy >= 0 && gy < P2H && (unsigned)gx < (unsigned)P2W)
      v = *(const uint4*)(X3 + (((size_t)b * P2H + gy) * P2W + gx) * 24 + part * 8);
    *(uint4*)(lin + px * 24 + part * 8) = v;
  }
  __syncthreads();

  const int wv = tid >> 6, ln = tid & 63, q = ln >> 4, nl = ln & 15;
  const half_t* cb0 = lin + 2 * nl * 24 + q * 8;
  const half_t* wA = wp + nl * 32 + q * 8;

  floatx4 acc[8];
  #pragma unroll
  for (int j = 0; j < 8; ++j) acc[j] = (floatx4){0.f, 0.f, 0.f, 0.f};

  #pragma unroll
  for (int ky = 0; ky < 5; ++ky) {
    #pragma unroll
    for (int kk = 0; kk < 4; ++kk) {
      half8 A = *(const half8*)(wA + (ky * 4 + kk) * 512);
      #pragma unroll
      for (int j = 0; j < 8; ++j) {
        const int g = j >> 2, phy = (j >> 1) & 1, phx = j & 1;
        half8 B = *(const half8*)(cb0 + (4 * wv + 2 * g + phy + ky) * 864 + phx * 24 + kk * 32);
        acc[j] = __builtin_amdgcn_mfma_f32_16x16x32_f16(A, B, acc[j], 0, 0, 0);
      }
    }
  }

  float bv[4], w5v[4];
  #pragma unroll
  for (int r = 0; r < 4; ++r) {
    int oc = q * 4 + r;
    bv[r]  = (oc < 10) ? bias[oc] : 0.f;
    w5v[r] = (oc < 10) ? w5[oc] : 0.f;
  }
  const float b5v = b5[0];
  const float* inb = in + (size_t)b * 3 * (IN_H * IN_W);

  #pragma unroll
  for (int g = 0; g < 2; ++g)
    #pragma unroll
    for (int phy = 0; phy < 2; ++phy) {
      const int y = ty0 + 4 * wv + 2 * g + phy;
      const int x0 = tx0 + 2 * nl;                     // phx=0 pixel; phx=1 is x0+1
      float s0 = 0.f, s1 = 0.f;
      #pragma unroll
      for (int r = 0; r < 4; ++r) {
        s0 += w5v[r] * fmaxf(acc[g * 4 + 2 * phy + 0][r] + bv[r], 0.f);
        s1 += w5v[r] * fmaxf(acc[g * 4 + 2 * phy + 1][r] + bv[r], 0.f);
      }
      s0 += __shfl_xor(s0, 16); s0 += __shfl_xor(s0, 32);
      s1 += __shfl_xor(s1, 16); s1 += __shfl_xor(s1, 32);
      if (q == 0) {
        // gray bilinear: input rows 4y+1,4y+2; cols 4x+1,4x+2 for x = x0, x0+1.
        const size_t cb = (size_t)(4 * y + 1) * IN_W + 4 * x0;
        float g0 = 0.f, g1 = 0.f;
        #pragma unroll
        for (int ch = 0; ch < 3; ++ch) {
          const float coef = (ch == 0) ? 0.299f : ((ch == 1) ? 0.587f : 0.114f);
          const float* qp = inb + (size_t)ch * (IN_H * IN_W);
          float4 a0 = *(const float4*)(qp + cb);
          float4 a1 = *(const float4*)(qp + cb + 4);
          float4 d0 = *(const float4*)(qp + cb + IN_W);
          float4 d1 = *(const float4*)(qp + cb + IN_W + 4);
          g0 += coef * (a0.y + a0.z + d0.y + d0.z);
          g1 += coef * (a1.y + a1.z + d1.y + d1.z);
        }
        float o0 = fmaxf(s0 + b5v + fmaxf(g0 * 0.25f, 0.f), 0.f);
        float o1 = fmaxf(s1 + b5v + fmaxf(g1 * 0.25f, 0.f), 0.f);
        *(float2*)(out + ((size_t)b * P2H + y) * P2W + x0) = make_float2(o0, o1);
      }
    }
}

extern "C" void kernel_launch(void* const* d_in, const int* in_sizes, int n_in,
                              void* d_out, int out_size, void* d_ws, size_t ws_size,
                              hipStream_t stream) {
  const float* input = (const float*)d_in[0];
  const float* w1 = (const float*)d_in[1];  const float* b1 = (const float*)d_in[2];
  const float* w2 = (const float*)d_in[3];  const float* b2 = (const float*)d_in[4];
  const float* w3 = (const float*)d_in[5];  const float* b3 = (const float*)d_in[6];
  const float* w4 = (const float*)d_in[7];  const float* b4 = (const float*)d_in[8];
  const float* w5 = (const float*)d_in[9];  const float* b5 = (const float*)d_in[10];
  float* out = (float*)d_out;
  char* ws = (char*)d_ws;

  half_t* P2h = (half_t*)(ws + OFF_P2);
  half_t* P1h = (half_t*)(ws + OFF_P1);
  half_t* X3h = (half_t*)(ws + OFF_X3);
  half_t* wp2 = (half_t*)(ws + OFF_W2);
  half_t* wp3 = (half_t*)(ws + OFF_W3);
  half_t* wp4 = (half_t*)(ws + OFF_W4);
  half_t* wp1 = (half_t*)(ws + OFF_W1);

  pack_weights<<<348, 256, 0, stream>>>(w2, w3, w4, w1, wp2, wp3, wp4, wp1);
  conv1_mfma<<<dim3(32, 24, 8), 256, 0, stream>>>(input, wp1, b1, P1h);
  conv2_mfma<<<dim3(16, 24, 8), 256, 0, stream>>>(P1h, wp2, b2, P2h);
  conv3_mfma<<<dim3(8, 24, 8), 256, 0, stream>>>(P2h, wp3, b3, X3h);
  conv4_mfma<<<dim3(8, 12, 8), 256, 0, stream>>>(X3h, wp4, b4, w5, b5, input, out);
}

// Round 11
// 324.817 us; speedup vs baseline: 1.7573x; 1.7573x over previous
//
#include <hip/hip_runtime.h>

// Res_MCNN_branch2 on gfx950 — all convs f16 MFMA implicit-GEMM (16x16x32).
// R20 = consolidation: conv1 R17-float4 staging + K-folded conv2/3/4 at
// __launch_bounds__(256,2). R19's (256,3) on conv2 spilled the 96-reg acc
// (VGPR squeezed to 84, FETCH/WRITE 563/698 MB) — occupancy for conv2 is
// now closed on BOTH sides: fat structure can't fit 3 waves (R14/R19 spill),
// thin structure doubles per-MFMA overhead (R15). (256,2) + K-fold is the
// accepted local optimum for conv2.
// Failure ledger (all reverted): R11 gload_lds DMA (22x FETCH), R12
// multi-tile (L2 thrash), R14 g-split (spill), R15 2-row waves (overhead),
// R16 direct-global (spill), R18 conv1 float2 staging (instr count), R19
// (256,3) forced occupancy (acc spill).
// Layouts: P1 NHWC24, P2 NHWC48, X3 NHWC24. conv4+conv5 fused (R13).

typedef _Float16 half_t;
typedef _Float16 half8 __attribute__((ext_vector_type(8)));
typedef float floatx4 __attribute__((ext_vector_type(4)));

#define IN_H 768
#define IN_W 1024
#define P1H 384
#define P1W 512
#define P2H 192
#define P2W 256

// workspace offsets (bytes)
#define OFF_P2 0ULL                 // f16 [8][192][256][48] = 37,748,736
#define OFF_P1 44040192ULL          // f16 [8][384][512][24] = 75,497,472
#define OFF_X3 44040192ULL          // reuse P1 region after conv2
#define OFF_W2 119537664ULL         // f16 [5][4][48][32] = 30,720 el (K-folded)
#define OFF_W3 119599104ULL         // f16 [5][8][32][32] = 40,960 el (K-folded)
#define OFF_W4 119681024ULL         // f16 [5][4][16][32] = 10,240 el (K-folded)
#define OFF_W1 119701504ULL         // f16 [7][32][32]    = 7,168 el

union PK4 { half_t h[4]; uint2 u; };
union U8 { half8 v; uint2 u[2]; };

// ---------------- weight pre-pack (fp32 OIHW -> f16 packed, linear) ----------------
__global__ __launch_bounds__(256) void pack_weights(
    const float* __restrict__ w2, const float* __restrict__ w3,
    const float* __restrict__ w4, const float* __restrict__ w1,
    half_t* __restrict__ wp2, half_t* __restrict__ wp3, half_t* __restrict__ wp4,
    half_t* __restrict__ wp1)
{
  int t = blockIdx.x * 256 + threadIdx.x;
  if (t < 30720) {                       // conv2 K-folded: [5 ky][4 kk][48 oc][32 k]
    int ky = t / 6144, r = t % 6144;
    int kk = r / 1536, r2 = r % 1536, oc = r2 >> 5, k = r2 & 31;
    int o = kk * 32 + k, p = o / 24, c = o % 24;   // pixel offset p (=kx), channel c
    float v = (oc < 40 && c < 20 && p < 5) ? w2[(oc * 20 + c) * 25 + ky * 5 + p] : 0.f;
    wp2[t] = (half_t)v;
  } else if (t < 71680) {                // conv3 K-folded: [5 ky][8 kk][32 oc][32 k]
    int u = t - 30720;
    int ky = u / 8192, r = u % 8192;
    int kk = r / 1024, r2 = r % 1024, oc = r2 >> 5, k = r2 & 31;
    int o = kk * 32 + k, p = o / 48, c = o % 48;   // pixel p, channel c in NHWC48
    float v = (oc < 20 && c < 40 && p < 5) ? w3[(oc * 40 + c) * 25 + ky * 5 + p] : 0.f;
    wp3[u] = (half_t)v;
  } else if (t < 81920) {                // conv4 K-folded: [5 ky][4 kk][16 oc][32 k]
    int u = t - 71680;
    int ky = u / 2048, r = u % 2048;
    int kk = r / 512, r2 = r % 512, oc = r2 >> 5, k = r2 & 31;
    int o = kk * 32 + k, p = o / 24, c = o % 24;
    float v = (oc < 10 && c < 20 && p < 5) ? w4[(oc * 20 + c) * 25 + ky * 5 + p] : 0.f;
    wp4[u] = (half_t)v;
  } else if (t < 89088) {                // conv1: [7][32][32], k = kx*4+c (unchanged)
    int u = t - 81920;
    int ky = u / 1024, r = u % 1024, oc = r >> 5, k = r & 31;
    int kx = k >> 2, c = k & 3;
    float v = (oc < 20 && c < 3 && kx < 7) ? w1[((oc * 3 + c) * 7 + ky) * 7 + kx] : 0.f;
    wp1[u] = (half_t)v;
  }
}

// ---------------- conv1 (3->20, 7x7, pad 3) MFMA + relu + pool -> P1 f16 NHWC24 ----------------
// 32-row tile, stage once (38x40 region, origin tx0-4 for float4 alignment),
// two K-loop passes p=0,1. Interior blocks: unguarded float4 staging (R17).
__global__ __launch_bounds__(256) void conv1_mfma(
    const float* __restrict__ in, const half_t* __restrict__ wp,
    const float* __restrict__ bias, half_t* __restrict__ P1)
{
  __shared__ __align__(16) half_t ltile[38 * 40 * 4];   // 12160 B, row stride 40 px
  const int b = blockIdx.z, ty0 = blockIdx.y * 32, tx0 = blockIdx.x * 32;
  const int tid = threadIdx.x;
  const int HW1 = IN_H * IN_W;

  const float* p0 = in + (size_t)b * 3 * HW1;
  const bool interior = (blockIdx.x >= 1) && (blockIdx.x <= 30) &&
                        (blockIdx.y >= 1) && (blockIdx.y <= 22);
  if (interior) {
    for (int i = tid; i < 380; i += 256) {              // 38 rows x 10 float4
      int r = i / 10, c4 = i - r * 10;
      const float* pr = p0 + (size_t)(ty0 - 3 + r) * IN_W + (tx0 - 4 + 4 * c4);
      float4 v0 = *(const float4*)(pr);
      float4 v1 = *(const float4*)(pr + HW1);
      float4 v2 = *(const float4*)(pr + 2 * HW1);
      PK4 a0, a1, a2, a3;
      a0.h[0] = (half_t)v0.x; a0.h[1] = (half_t)v1.x; a0.h[2] = (half_t)v2.x; a0.h[3] = (half_t)0.f;
      a1.h[0] = (half_t)v0.y; a1.h[1] = (half_t)v1.y; a1.h[2] = (half_t)v2.y; a1.h[3] = (half_t)0.f;
      a2.h[0] = (half_t)v0.z; a2.h[1] = (half_t)v1.z; a2.h[2] = (half_t)v2.z; a2.h[3] = (half_t)0.f;
      a3.h[0] = (half_t)v0.w; a3.h[1] = (half_t)v1.w; a3.h[2] = (half_t)v2.w; a3.h[3] = (half_t)0.f;
      uint4* dst = (uint4*)(ltile + (r * 40 + 4 * c4) * 4);
      dst[0] = make_uint4(a0.u.x, a0.u.y, a1.u.x, a1.u.y);
      dst[1] = make_uint4(a2.u.x, a2.u.y, a3.u.x, a3.u.y);
    }
  } else {
    for (int i = tid; i < 1520; i += 256) {             // 38 rows x 40 cols, guarded
      int r = i / 40, c = i - r * 40;
      int gy = ty0 - 3 + r, gx = tx0 - 4 + c;
      float v0 = 0.f, v1 = 0.f, v2 = 0.f;
      if (gy >= 0 && gy < IN_H && (unsigned)gx < (unsigned)IN_W) {
        size_t o = (size_t)gy * IN_W + gx;
        v0 = p0[o];
        v1 = p0[o + HW1];
        v2 = p0[o + 2 * HW1];
      }
      PK4 pk;
      pk.h[0] = (half_t)v0; pk.h[1] = (half_t)v1;
      pk.h[2] = (half_t)v2; pk.h[3] = (half_t)0.f;
      *(uint2*)(ltile + (r * 40 + c) * 4) = pk.u;
    }
  }
  __syncthreads();

  const int wv = tid >> 6, ln = tid & 63, q = ln >> 4, nl = ln & 15;
  const int cbase = (2 * nl + 2 * q + 1) * 4;           // +1: tile origin tx0-4
  const half_t* wA = wp + nl * 32 + q * 8;

  floatx4 bv[2];
  #pragma unroll
  for (int mt = 0; mt < 2; ++mt)
    #pragma unroll
    for (int r = 0; r < 4; ++r) {
      int oc = mt * 16 + q * 4 + r;
      bv[mt][r] = (oc < 20) ? bias[oc] : 0.f;
    }
  const int pc = (tx0 >> 1) + nl;

  #pragma unroll
  for (int p = 0; p < 2; ++p) {
    const int rbase = p * 16 + 4 * wv;            // ltile row of this pass/wave
    U8 frag[4][2];
    #pragma unroll
    for (int d = 0; d < 4; ++d) {
      const half_t* rp = ltile + (rbase + d) * 160 + cbase;
      #pragma unroll
      for (int phx = 0; phx < 2; ++phx) {
        frag[d][phx].u[0] = *(const uint2*)(rp + phx * 4);
        frag[d][phx].u[1] = *(const uint2*)(rp + phx * 4 + 4);
      }
    }
    half8 Abuf[2][2];
    Abuf[0][0] = *(const half8*)(wA);
    Abuf[0][1] = *(const half8*)(wA + 512);
    floatx4 acc[2][8];
    #pragma unroll
    for (int mt = 0; mt < 2; ++mt)
      #pragma unroll
      for (int j = 0; j < 8; ++j) acc[mt][j] = (floatx4){0.f, 0.f, 0.f, 0.f};

    #pragma unroll
    for (int ky = 0; ky < 7; ++ky) {
      if (ky < 6) {
        Abuf[(ky + 1) & 1][0] = *(const half8*)(wA + (ky + 1) * 1024);
        Abuf[(ky + 1) & 1][1] = *(const half8*)(wA + (ky + 1) * 1024 + 512);
      }
      #pragma unroll
      for (int j = 0; j < 8; ++j) {
        const int g = j >> 2, ph = j & 3, phy = ph >> 1, phx = ph & 1;
        half8 B = frag[(2 * g + phy + ky) & 3][phx].v;
        acc[0][j] = __builtin_amdgcn_mfma_f32_16x16x32_f16(Abuf[ky & 1][0], B, acc[0][j], 0, 0, 0);
        acc[1][j] = __builtin_amdgcn_mfma_f32_16x16x32_f16(Abuf[ky & 1][1], B, acc[1][j], 0, 0, 0);
      }
      if (ky < 6) {                               // slide: ltile row rbase+ky+4 -> slot ky&3
        const half_t* rp = ltile + (rbase + ky + 4) * 160 + cbase;
        #pragma unroll
        for (int phx = 0; phx < 2; ++phx) {
          frag[ky & 3][phx].u[0] = *(const uint2*)(rp + phx * 4);
          frag[ky & 3][phx].u[1] = *(const uint2*)(rp + phx * 4 + 4);
        }
      }
    }

    const int pr0 = (ty0 >> 1) + 8 * p + 2 * wv;
    #pragma unroll
    for (int g = 0; g < 2; ++g) {
      size_t pxbase = (((size_t)b * P1H + pr0 + g) * P1W + pc) * 24;
      PK4 pk0;
      #pragma unroll
      for (int r = 0; r < 4; ++r) {
        float x = fmaxf(fmaxf(acc[0][g * 4 + 0][r], acc[0][g * 4 + 1][r]),
                        fmaxf(acc[0][g * 4 + 2][r], acc[0][g * 4 + 3][r]));
        pk0.h[r] = (half_t)fmaxf(x + bv[0][r], 0.f);
      }
      *(uint2*)(P1 + pxbase + q * 4) = pk0.u;           // oc 0..15
      if (q < 2) {                                      // oc 16..19 real, 20..23 = 0
        PK4 pk1;
        #pragma unroll
        for (int r = 0; r < 4; ++r) {
          float x = fmaxf(fmaxf(acc[1][g * 4 + 0][r], acc[1][g * 4 + 1][r]),
                          fmaxf(acc[1][g * 4 + 2][r], acc[1][g * 4 + 3][r]));
          pk1.h[r] = (half_t)fmaxf(x + bv[1][r], 0.f);
        }
        *(uint2*)(P1 + pxbase + 16 + q * 4) = pk1.u;
      }
    }
  }
}

// ---------------- conv2 (20->40, 5x5) MFMA + relu + pool -> P2 f16 NHWC48 ----------------
// K-folded (R17): 4 K=32 steps per ky over the contiguous 120-half span.
// Output NHWC48: mt=0..2 covers exactly 48 oc (40 real + 8 zero-weight pad).
// (256,2): acc[3][8]=96 regs CANNOT fit 3 waves/SIMD (R19 spill proof).
__global__ __launch_bounds__(256, 2) void conv2_mfma(
    const half_t* __restrict__ P1, const half_t* __restrict__ wp,
    const float* __restrict__ bias, half_t* __restrict__ P2)
{
  __shared__ __align__(16) half_t lin[20 * 36 * 24 + 16];   // 34592 B
  const int b = blockIdx.z, ty0 = blockIdx.y * 16, tx0 = blockIdx.x * 32;
  const int tid = threadIdx.x;
  if (tid < 16) lin[20 * 36 * 24 + tid] = (half_t)0.f;
  for (int i = tid; i < 2160; i += 256) {              // 720 px x 3 uint4
    int px = i / 3, part = i - px * 3;
    int row = px / 36, col = px - row * 36;
    int gy = ty0 - 2 + row, gx = tx0 - 2 + col;
    uint4 v = make_uint4(0, 0, 0, 0);
    if (gy >= 0 && gy < P1H && (unsigned)gx < (unsigned)P1W)
      v = *(const uint4*)(P1 + (((size_t)b * P1H + gy) * P1W + gx) * 24 + part * 8);
    *(uint4*)(lin + px * 24 + part * 8) = v;
  }
  __syncthreads();

  const int wv = tid >> 6, ln = tid & 63, q = ln >> 4, nl = ln & 15;
  const half_t* cb0 = lin + 2 * nl * 24 + q * 8;       // span base, phx=0
  const half_t* wA = wp + nl * 32 + q * 8;

  floatx4 acc[3][8];
  #pragma unroll
  for (int mt = 0; mt < 3; ++mt)
    #pragma unroll
    for (int j = 0; j < 8; ++j) acc[mt][j] = (floatx4){0.f, 0.f, 0.f, 0.f};

  #pragma unroll
  for (int ky = 0; ky < 5; ++ky) {
    #pragma unroll
    for (int kk = 0; kk < 4; ++kk) {
      const half_t* wt = wA + (ky * 4 + kk) * 1536;
      half8 A0 = *(const half8*)(wt);
      half8 A1 = *(const half8*)(wt + 512);
      half8 A2 = *(const half8*)(wt + 1024);
      #pragma unroll
      for (int j = 0; j < 8; ++j) {
        const int g = j >> 2, phy = (j >> 1) & 1, phx = j & 1;
        half8 B = *(const half8*)(cb0 + (4 * wv + 2 * g + phy + ky) * 864 + phx * 24 + kk * 32);
        acc[0][j] = __builtin_amdgcn_mfma_f32_16x16x32_f16(A0, B, acc[0][j], 0, 0, 0);
        acc[1][j] = __builtin_amdgcn_mfma_f32_16x16x32_f16(A1, B, acc[1][j], 0, 0, 0);
        acc[2][j] = __builtin_amdgcn_mfma_f32_16x16x32_f16(A2, B, acc[2][j], 0, 0, 0);
      }
    }
  }

  floatx4 bv[3];
  #pragma unroll
  for (int mt = 0; mt < 3; ++mt)
    #pragma unroll
    for (int r = 0; r < 4; ++r) {
      int oc = mt * 16 + q * 4 + r;
      bv[mt][r] = (oc < 40) ? bias[oc] : 0.f;
    }
  const int pr0 = (ty0 >> 1) + 2 * wv;
  const int pc = (tx0 >> 1) + nl;
  #pragma unroll
  for (int g = 0; g < 2; ++g) {
    size_t pxbase = (((size_t)b * P2H + pr0 + g) * P2W + pc) * 48;
    #pragma unroll
    for (int mt = 0; mt < 3; ++mt) {
      PK4 pk;
      #pragma unroll
      for (int r = 0; r < 4; ++r) {
        float x = fmaxf(fmaxf(acc[mt][g * 4 + 0][r], acc[mt][g * 4 + 1][r]),
                        fmaxf(acc[mt][g * 4 + 2][r], acc[mt][g * 4 + 3][r]));
        pk.h[r] = (half_t)fmaxf(x + bv[mt][r], 0.f);   // oc 40..47: 0+0 -> 0 pad
      }
      *(uint2*)(P2 + pxbase + mt * 16 + q * 4) = pk.u;
    }
  }
}

// ---------------- conv3 (40->20, 5x5) MFMA + relu -> X3 f16 NHWC24 ----------------
// K-folded: per ky the 5 taps are one contiguous 240-half NHWC48 span ->
// 8 K=32 steps (was 10). Weights [5][8][32][32], slot o -> (px o/48, ch o%48),
// zero where ch>=40 or px>=5. Worst read = half 20751 < 20752 (zero tail).
__global__ __launch_bounds__(256, 2) void conv3_mfma(
    const half_t* __restrict__ P2, const half_t* __restrict__ wp,
    const float* __restrict__ bias, half_t* __restrict__ X3)
{
  __shared__ __align__(16) half_t lin[12 * 36 * 48 + 16];   // 41504 B
  const int b = blockIdx.z, ty0 = blockIdx.y * 8, tx0 = blockIdx.x * 32;
  const int tid = threadIdx.x;
  if (tid < 16) lin[12 * 36 * 48 + tid] = (half_t)0.f;
  for (int i = tid; i < 2592; i += 256) {              // 432 px x 6 uint4
    int px = i / 6, part = i - px * 6;
    int row = px / 36, col = px - row * 36;
    int gy = ty0 - 2 + row, gx = tx0 - 2 + col;
    uint4 v = make_uint4(0, 0, 0, 0);
    if (gy >= 0 && gy < P2H && (unsigned)gx < (unsigned)P2W)
      v = *(const uint4*)(P2 + (((size_t)b * P2H + gy) * P2W + gx) * 48 + part * 8);
    *(uint4*)(lin + px * 48 + part * 8) = v;
  }
  __syncthreads();

  const int wv = tid >> 6, ln = tid & 63, q = ln >> 4, nl = ln & 15;
  const half_t* cb0 = lin + 2 * nl * 48 + q * 8;       // span base, phx=0
  const half_t* wA = wp + nl * 32 + q * 8;

  floatx4 acc[2][4];
  #pragma unroll
  for (int mt = 0; mt < 2; ++mt)
    #pragma unroll
    for (int j = 0; j < 4; ++j) acc[mt][j] = (floatx4){0.f, 0.f, 0.f, 0.f};

  #pragma unroll
  for (int ky = 0; ky < 5; ++ky) {
    #pragma unroll
    for (int kk = 0; kk < 8; ++kk) {
      const half_t* wt = wA + (ky * 8 + kk) * 1024;
      half8 A0 = *(const half8*)(wt);
      half8 A1 = *(const half8*)(wt + 512);
      #pragma unroll
      for (int j = 0; j < 4; ++j) {
        const int phy = j >> 1, phx = j & 1;
        half8 B = *(const half8*)(cb0 + (2 * wv + phy + ky) * 1728 + phx * 48 + kk * 32);
        acc[0][j] = __builtin_amdgcn_mfma_f32_16x16x32_f16(A0, B, acc[0][j], 0, 0, 0);
        acc[1][j] = __builtin_amdgcn_mfma_f32_16x16x32_f16(A1, B, acc[1][j], 0, 0, 0);
      }
    }
  }

  floatx4 bv[2];
  #pragma unroll
  for (int mt = 0; mt < 2; ++mt)
    #pragma unroll
    for (int r = 0; r < 4; ++r) {
      int oc = mt * 16 + q * 4 + r;
      bv[mt][r] = (oc < 20) ? bias[oc] : 0.f;
    }
  #pragma unroll
  for (int j = 0; j < 4; ++j) {
    const int phy = j >> 1, phx = j & 1;
    int y = ty0 + 2 * wv + phy, x = tx0 + 2 * nl + phx;
    size_t pxbase = (((size_t)b * P2H + y) * P2W + x) * 24;
    #pragma unroll
    for (int mt = 0; mt < 2; ++mt) {
      if (mt == 1 && q >= 2) continue;                 // record is 24 halves
      floatx4 v = acc[mt][j];
      PK4 pk;
      #pragma unroll
      for (int r = 0; r < 4; ++r) pk.h[r] = (half_t)fmaxf(v[r] + bv[mt][r], 0.f);
      *(uint2*)(X3 + pxbase + mt * 16 + q * 4) = pk.u; // oc 20..23 auto-zero
    }
  }
}

// ---------------- conv4 (20->10, 5x5) + conv5 (10->1, 1x1) + gray residual + relu ----------------
// K-folded (R17, mt=1): 160 MFMA/wave. X3 records 24 halves.
// Fused epilogue: q-lanes hold the same pixel (different oc) -> per-lane w5
// partial, shfl_xor(16)+shfl_xor(32) reduce, q==0 adds gray + writes out.
__global__ __launch_bounds__(256, 2) void conv4_mfma(
    const half_t* __restrict__ X3, const half_t* __restrict__ wp,
    const float* __restrict__ bias, const float* __restrict__ w5,
    const float* __restrict__ b5, const float* __restrict__ in,
    float* __restrict__ out)
{
  __shared__ __align__(16) half_t lin[20 * 36 * 24 + 16];   // 34592 B
  const int b = blockIdx.z, ty0 = blockIdx.y * 16, tx0 = blockIdx.x * 32;
  const int tid = threadIdx.x;
  if (tid < 16) lin[20 * 36 * 24 + tid] = (half_t)0.f;
  for (int i = tid; i < 2160; i += 256) {
    int px = i / 3, part = i - px * 3;
    int row = px / 36, col = px - row * 36;
    int gy = ty0 - 2 + row, gx = tx0 - 2 + col;
    uint4 v = make_uint4(0, 0, 0, 0);
    if (gy >= 0 && gy < P2H && (unsigned)gx < (unsigned)P2W)
      v = *(const uint4*)(X3 + (((size_t)b * P2H + gy) * P2W + gx) * 24 + part * 8);
    *(uint4*)(lin + px * 24 + part * 8) = v;
  }
  __syncthreads();

  const int wv = tid >> 6, ln = tid & 63, q = ln >> 4, nl = ln & 15;
  const half_t* cb0 = lin + 2 * nl * 24 + q * 8;
  const half_t* wA = wp + nl * 32 + q * 8;

  floatx4 acc[8];
  #pragma unroll
  for (int j = 0; j < 8; ++j) acc[j] = (floatx4){0.f, 0.f, 0.f, 0.f};

  #pragma unroll
  for (int ky = 0; ky < 5; ++ky) {
    #pragma unroll
    for (int kk = 0; kk < 4; ++kk) {
      half8 A = *(const half8*)(wA + (ky * 4 + kk) * 512);
      #pragma unroll
      for (int j = 0; j < 8; ++j) {
        const int g = j >> 2, phy = (j >> 1) & 1, phx = j & 1;
        half8 B = *(const half8*)(cb0 + (4 * wv + 2 * g + phy + ky) * 864 + phx * 24 + kk * 32);
        acc[j] = __builtin_amdgcn_mfma_f32_16x16x32_f16(A, B, acc[j], 0, 0, 0);
      }
    }
  }

  float bv[4], w5v[4];
  #pragma unroll
  for (int r = 0; r < 4; ++r) {
    int oc = q * 4 + r;
    bv[r]  = (oc < 10) ? bias[oc] : 0.f;
    w5v[r] = (oc < 10) ? w5[oc] : 0.f;
  }
  const float b5v = b5[0];
  const float* inb = in + (size_t)b * 3 * (IN_H * IN_W);

  #pragma unroll
  for (int g = 0; g < 2; ++g)
    #pragma unroll
    for (int phy = 0; phy < 2; ++phy) {
      const int y = ty0 + 4 * wv + 2 * g + phy;
      const int x0 = tx0 + 2 * nl;                     // phx=0 pixel; phx=1 is x0+1
      float s0 = 0.f, s1 = 0.f;
      #pragma unroll
      for (int r = 0; r < 4; ++r) {
        s0 += w5v[r] * fmaxf(acc[g * 4 + 2 * phy + 0][r] + bv[r], 0.f);
        s1 += w5v[r] * fmaxf(acc[g * 4 + 2 * phy + 1][r] + bv[r], 0.f);
      }
      s0 += __shfl_xor(s0, 16); s0 += __shfl_xor(s0, 32);
      s1 += __shfl_xor(s1, 16); s1 += __shfl_xor(s1, 32);
      if (q == 0) {
        // gray bilinear: input rows 4y+1,4y+2; cols 4x+1,4x+2 for x = x0, x0+1.
        const size_t cb = (size_t)(4 * y + 1) * IN_W + 4 * x0;
        float g0 = 0.f, g1 = 0.f;
        #pragma unroll
        for (int ch = 0; ch < 3; ++ch) {
          const float coef = (ch == 0) ? 0.299f : ((ch == 1) ? 0.587f : 0.114f);
          const float* qp = inb + (size_t)ch * (IN_H * IN_W);
          float4 a0 = *(const float4*)(qp + cb);
          float4 a1 = *(const float4*)(qp + cb + 4);
          float4 d0 = *(const float4*)(qp + cb + IN_W);
          float4 d1 = *(const float4*)(qp + cb + IN_W + 4);
          g0 += coef * (a0.y + a0.z + d0.y + d0.z);
          g1 += coef * (a1.y + a1.z + d1.y + d1.z);
        }
        float o0 = fmaxf(s0 + b5v + fmaxf(g0 * 0.25f, 0.f), 0.f);
        float o1 = fmaxf(s1 + b5v + fmaxf(g1 * 0.25f, 0.f), 0.f);
        *(float2*)(out + ((size_t)b * P2H + y) * P2W + x0) = make_float2(o0, o1);
      }
    }
}

extern "C" void kernel_launch(void* const* d_in, const int* in_sizes, int n_in,
                              void* d_out, int out_size, void* d_ws, size_t ws_size,
                              hipStream_t stream) {
  const float* input = (const float*)d_in[0];
  const float* w1 = (const float*)d_in[1];  const float* b1 = (const float*)d_in[2];
  const float* w2 = (const float*)d_in[3];  const float* b2 = (const float*)d_in[4];
  const float* w3 = (const float*)d_in[5];  const float* b3 = (const float*)d_in[6];
  const float* w4 = (const float*)d_in[7];  const float* b4 = (const float*)d_in[8];
  const float* w5 = (const float*)d_in[9];  const float* b5 = (const float*)d_in[10];
  float* out = (float*)d_out;
  char* ws = (char*)d_ws;

  half_t* P2h = (half_t*)(ws + OFF_P2);
  half_t* P1h = (half_t*)(ws + OFF_P1);
  half_t* X3h = (half_t*)(ws + OFF_X3);
  half_t* wp2 = (half_t*)(ws + OFF_W2);
  half_t* wp3 = (half_t*)(ws + OFF_W3);
  half_t* wp4 = (half_t*)(ws + OFF_W4);
  half_t* wp1 = (half_t*)(ws + OFF_W1);

  pack_weights<<<348, 256, 0, stream>>>(w2, w3, w4, w1, wp2, wp3, wp4, wp1);
  conv1_mfma<<<dim3(32, 24, 8), 256, 0, stream>>>(input, wp1, b1, P1h);
  conv2_mfma<<<dim3(16, 24, 8), 256, 0, stream>>>(P1h, wp2, b2, P2h);
  conv3_mfma<<<dim3(8, 24, 8), 256, 0, stream>>>(P2h, wp3, b3, X3h);
  conv4_mfma<<<dim3(8, 12, 8), 256, 0, stream>>>(X3h, wp4, b4, w5, b5, input, out);
}